// Round 6
// baseline (243.576 us; speedup 1.0000x reference)
//
#include <hip/hip_runtime.h>
#include <hip/hip_bf16.h>

#define TOKENS 512
#define IN_F 8192
#define OUT_F 8192
#define RANK 64
#define NNZ 8192

#define BM 128
#define BN 32
#define BK 64
#define NT (IN_F / BK)   // 128

typedef __attribute__((ext_vector_type(8))) short short8;
typedef __attribute__((ext_vector_type(4))) float f32x4;
typedef __attribute__((ext_vector_type(4))) int int4v;

__device__ __forceinline__ unsigned short f2bf(float f) {
  unsigned int u = __builtin_bit_cast(unsigned int, f);
  u += 0x7FFFu + ((u >> 16) & 1u);
  return (unsigned short)(u >> 16);
}
__device__ __forceinline__ float bf2f(unsigned short b) {
  unsigned int u = ((unsigned int)b) << 16;
  return __builtin_bit_cast(float, u);
}

__device__ __forceinline__ void gload_lds16(const void* g, void* l) {
  __builtin_amdgcn_global_load_lds(
      (const __attribute__((address_space(1))) unsigned int*)(g),
      (__attribute__((address_space(3))) unsigned int*)(l), 16, 0, 0);
}

#define WAIT_VM(n) asm volatile("s_waitcnt vmcnt(" #n ")" ::: "memory")
#define WAIT_LGKM0 asm volatile("s_waitcnt lgkmcnt(0)" ::: "memory")

// K1: quantize x -> x_q; bf16 copy (lr1/outlier) and i8 copy (gemm)
__global__ __launch_bounds__(256) void k_quant(const float* __restrict__ x,
                                               const float* __restrict__ smooth,
                                               const float* __restrict__ act,
                                               unsigned short* __restrict__ Abf,
                                               unsigned char* __restrict__ Aq) {
  int idx = blockIdx.x * 256 + threadIdx.x;
  int base = idx * 4;
  int col = base & (IN_F - 1);
  float a = act[0];
  float4 xx = *(const float4*)(x + base);
  float4 ss = *(const float4*)(smooth + col);
  float q0 = fminf(fmaxf(rintf((xx.x / ss.x) / a), -128.f), 127.f);
  float q1 = fminf(fmaxf(rintf((xx.y / ss.y) / a), -128.f), 127.f);
  float q2 = fminf(fmaxf(rintf((xx.z / ss.z) / a), -128.f), 127.f);
  float q3 = fminf(fmaxf(rintf((xx.w / ss.w) / a), -128.f), 127.f);
  ushort4 o;
  o.x = f2bf(q0); o.y = f2bf(q1); o.z = f2bf(q2); o.w = f2bf(q3);
  *(ushort4*)(Abf + base) = o;
  int i0 = (int)q0, i1 = (int)q1, i2 = (int)q2, i3 = (int)q3;
  unsigned int p = (i0 & 0xFF) | ((i1 & 0xFF) << 8) | ((i2 & 0xFF) << 16) |
                   ((unsigned)(i3 & 0xFF) << 24);
  *(unsigned int*)(Aq + base) = p;
}

// K2: t[512][64] = (x_dq @ V) * S*a   (64 blocks, atomic K-split accum)
__global__ __launch_bounds__(256) void k_lr1(const unsigned short* __restrict__ Abf,
                                             const float* __restrict__ V,
                                             const float* __restrict__ S,
                                             const float* __restrict__ act,
                                             float* __restrict__ t) {
  int bid = blockIdx.x;
  int mb = (bid & 3) * 128;
  int kb0 = (bid >> 2) * 512;
  int tid = threadIdx.x, w = tid >> 6, l = tid & 63;
  int lr = l & 15, lg = l >> 4;
  f32x4 acc[2][4] = {};
  for (int ks = 0; ks < 16; ++ks) {
    int kb = kb0 + ks * 32;
    short8 af[2];
#pragma unroll
    for (int fi = 0; fi < 2; ++fi) {
      int row = mb + w * 32 + fi * 16 + lr;
      af[fi] = *(const short8*)(Abf + (size_t)row * IN_F + kb + lg * 8);
    }
    short8 bfr[4];
#pragma unroll
    for (int fj = 0; fj < 4; ++fj) {
      int rk = fj * 16 + lr;
      short8 bv;
#pragma unroll
      for (int j = 0; j < 8; ++j)
        bv[j] = (short)f2bf(V[(size_t)(kb + lg * 8 + j) * RANK + rk]);
      bfr[fj] = bv;
    }
#pragma unroll
    for (int fi = 0; fi < 2; ++fi)
#pragma unroll
      for (int fj = 0; fj < 4; ++fj)
        acc[fi][fj] = __builtin_amdgcn_mfma_f32_16x16x32_bf16(af[fi], bfr[fj], acc[fi][fj], 0, 0, 0);
  }
  float a = act[0];
#pragma unroll
  for (int fi = 0; fi < 2; ++fi)
#pragma unroll
    for (int fj = 0; fj < 4; ++fj) {
      int rk = fj * 16 + lr;
      float sc = a * S[rk];
#pragma unroll
      for (int r = 0; r < 4; ++r) {
        int tok = mb + w * 32 + fi * 16 + lg * 4 + r;
        atomicAdd(t + tok * RANK + rk, acc[fi][fj][r] * sc);
      }
    }
}

// K3: out = bias + t @ U^T   (first writer of out)
__global__ __launch_bounds__(256) void k_lr2(const float* __restrict__ t,
                                             const float* __restrict__ U,
                                             const float* __restrict__ bias,
                                             float* __restrict__ out) {
  int bid = blockIdx.x;
  int mb = (bid & 3) * 128;
  int nb = (bid >> 2) * 128;
  int tid = threadIdx.x, w = tid >> 6, l = tid & 63;
  int lr = l & 15, lg = l >> 4;
  int wm = w >> 1, wn = w & 1;
  f32x4 acc[4][4] = {};
#pragma unroll
  for (int kk = 0; kk < 2; ++kk) {
    short8 af[4], bfr[4];
#pragma unroll
    for (int fi = 0; fi < 4; ++fi) {
      int row = mb + wm * 64 + fi * 16 + lr;
      const float4* tp = (const float4*)(t + (size_t)row * RANK + kk * 32 + lg * 8);
      float4 t0 = tp[0], t1 = tp[1];
      af[fi][0] = f2bf(t0.x); af[fi][1] = f2bf(t0.y);
      af[fi][2] = f2bf(t0.z); af[fi][3] = f2bf(t0.w);
      af[fi][4] = f2bf(t1.x); af[fi][5] = f2bf(t1.y);
      af[fi][6] = f2bf(t1.z); af[fi][7] = f2bf(t1.w);
    }
#pragma unroll
    for (int fj = 0; fj < 4; ++fj) {
      int row = nb + wn * 64 + fj * 16 + lr;
      const float4* up = (const float4*)(U + (size_t)row * RANK + kk * 32 + lg * 8);
      float4 u0 = up[0], u1 = up[1];
      bfr[fj][0] = f2bf(u0.x); bfr[fj][1] = f2bf(u0.y);
      bfr[fj][2] = f2bf(u0.z); bfr[fj][3] = f2bf(u0.w);
      bfr[fj][4] = f2bf(u1.x); bfr[fj][5] = f2bf(u1.y);
      bfr[fj][6] = f2bf(u1.z); bfr[fj][7] = f2bf(u1.w);
    }
#pragma unroll
    for (int fi = 0; fi < 4; ++fi)
#pragma unroll
      for (int fj = 0; fj < 4; ++fj)
        acc[fi][fj] = __builtin_amdgcn_mfma_f32_16x16x32_bf16(af[fi], bfr[fj], acc[fi][fj], 0, 0, 0);
  }
#pragma unroll
  for (int fj = 0; fj < 4; ++fj) {
    int o = nb + wn * 64 + fj * 16 + lr;
    float b = bias[o];
#pragma unroll
    for (int fi = 0; fi < 4; ++fi)
#pragma unroll
      for (int r = 0; r < 4; ++r) {
        int tok = mb + wm * 64 + fi * 16 + lg * 4 + r;
        out[(size_t)tok * OUT_F + o] = b + acc[fi][fj][r];
      }
  }
}

// K4: outliers — per-token LDS accumulator + one coalesced RMW pass
__global__ __launch_bounds__(256) void k_outlier(const unsigned short* __restrict__ Abf,
                                                 const int* __restrict__ rows,
                                                 const int* __restrict__ cols,
                                                 const float* __restrict__ vals,
                                                 const float* __restrict__ act,
                                                 float* __restrict__ out) {
  __shared__ float accr[OUT_F];
  int tk = blockIdx.x;
  for (int i = threadIdx.x; i < OUT_F; i += 256) accr[i] = 0.f;
  __syncthreads();
  float a = act[0];
  for (int i = threadIdx.x; i < NNZ; i += 256) {
    int r = rows[i], c = cols[i];
    float v = vals[i];
    float xq = bf2f(Abf[(size_t)tk * IN_F + c]);
    atomicAdd(accr + r, a * xq * v);
  }
  __syncthreads();
  float* orow = out + (size_t)tk * OUT_F;
  for (int i = threadIdx.x; i < OUT_F; i += 256) orow[i] += accr[i];
}

// K5: out += x_q @ Wq^T * (a*wscale[o]); i8 MFMA, BM=128, BN=32, KSPLIT=1,
// 4 blocks/CU (the occupancy lever), counted-vmcnt pipeline, raw s_barrier,
// setprio, free-2-way LDS swizzle. W read exactly once. Unique writer.
__global__ __launch_bounds__(512, 8) void k_gemm(const unsigned char* __restrict__ Aq,
                                                 const int* __restrict__ W,
                                                 const float* __restrict__ wscale,
                                                 const float* __restrict__ act,
                                                 float* __restrict__ out) {
  __shared__ __align__(16) unsigned char As[2][BM * BK];  // 16 KB
  __shared__ __align__(16) unsigned char Bs[2][BN * BK];  // 4 KB

  // XCD-chunked bijective decode: 2 XCDs share one mb (A slice 1MB, L2-fit)
  int d = blockIdx.x;
  int wg = (d & 7) * 128 + (d >> 3);  // 0..1023
  int mb = wg >> 8;                   // 0..3
  int nb = wg & 255;                  // 0..255

  int tid = threadIdx.x, w = tid >> 6, l = tid & 63;
  int lr = l & 15, lg = l >> 4;
  int wm = w >> 1, wn = w & 1;        // 4M x 2N waves; wave tile 32x16

  int4v acc[2] = {};
  int4v wa, wb;

  const int rB = tid >> 4;            // W row 0..31
  const int kcB = (tid & 15) * 4;     // elem offset within BK

  auto LOAD_W = [&](int4v& wr, int kb) {
    wr = *(const int4v*)(W + (size_t)(nb * BN + rB) * IN_F + kb + kcB);
  };
  // A i8 -> LDS direct; linear dest, pre-swizzled source (u ^= (r>>1)&3)
  auto STAGE_A = [&](int buf, int kb) {
    int r = tid >> 2, up = tid & 3;
    int u = up ^ ((r >> 1) & 3);
    gload_lds16(Aq + (size_t)(mb * BM + r) * IN_F + kb + u * 16,
                &As[buf][(size_t)(w * 64) * 16]);
  };
  auto WRITE_B = [&](int buf, int4v wr) {
    unsigned int w0 = 0;
#pragma unroll
    for (int j = 0; j < 4; ++j) w0 |= ((unsigned)(wr[j] & 0xFF)) << (8 * j);
    int u = kcB >> 4, off = kcB & 15;
    int us = u ^ ((rB >> 1) & 3);
    *(unsigned int*)(&Bs[buf][(size_t)rB * BK + us * 16 + off]) = w0;
  };
  auto LDFA = [&](int buf, int row) -> int4v {
    int u = lg ^ ((row >> 1) & 3);
    return *(const int4v*)(&As[buf][(size_t)row * BK + u * 16]);
  };
  auto LDFB = [&](int buf, int row) -> int4v {
    int u = lg ^ ((row >> 1) & 3);
    return *(const int4v*)(&Bs[buf][(size_t)row * BK + u * 16]);
  };
  auto COMPUTE = [&](int buf) {
    __builtin_amdgcn_s_setprio(1);
    int4v b0 = LDFB(buf, wn * 16 + lr);
#pragma unroll
    for (int fi = 0; fi < 2; ++fi) {
      int4v af = LDFA(buf, wm * 32 + fi * 16 + lr);
      acc[fi] = __builtin_amdgcn_mfma_i32_16x16x64_i8(af, b0, acc[fi], 0, 0, 0);
    }
    __builtin_amdgcn_s_setprio(0);
  };

  // prologue — steady-state invariant at loop top: 1 W load outstanding
  LOAD_W(wa, 0);                   // [W0]
  STAGE_A(0, 0);                   // [W0, A0]
  WAIT_VM(1);                      // W0 ready
  WRITE_B(0, wa);
  LOAD_W(wa, BK);                  // [A0, W1]
  WAIT_VM(1);                      // A0 staged
  WAIT_LGKM0;
  __builtin_amdgcn_s_barrier();

#define ITER(kt, CUR, wcur, wnxt)                                   \
  {                                                                 \
    STAGE_A(CUR ^ 1, (((kt) + 1) & (NT - 1)) * BK);                 \
    LOAD_W(wnxt, (((kt) + 2) & (NT - 1)) * BK);                     \
    COMPUTE(CUR);                                                   \
    WAIT_VM(2);                                                     \
    WRITE_B(CUR ^ 1, wcur);                                         \
    WAIT_VM(1);                                                     \
    WAIT_LGKM0;                                                     \
    __builtin_amdgcn_s_barrier();                                   \
  }

  for (int kt = 0; kt < NT; kt += 2) {
    ITER(kt, 0, wa, wb);
    ITER(kt + 1, 1, wb, wa);
  }
#undef ITER

  float a = act[0];
  int o = nb * BN + wn * 16 + lr;
  float sc = a * wscale[o];
#pragma unroll
  for (int fi = 0; fi < 2; ++fi)
#pragma unroll
    for (int rr = 0; rr < 4; ++rr) {
      int tok = mb * BM + wm * 32 + fi * 16 + lg * 4 + rr;
      float* p = out + (size_t)tok * OUT_F + o;
      *p += (float)acc[fi][rr] * sc;   // unique writer, no atomic
    }
}

extern "C" void kernel_launch(void* const* d_in, const int* in_sizes, int n_in,
                              void* d_out, int out_size, void* d_ws, size_t ws_size,
                              hipStream_t stream) {
  const float* x = (const float*)d_in[0];
  const int* W = (const int*)d_in[1];
  const float* wscale = (const float*)d_in[2];
  const float* smooth = (const float*)d_in[3];
  const float* act = (const float*)d_in[4];
  const int* orow = (const int*)d_in[5];
  const int* ocol = (const int*)d_in[6];
  const float* oval = (const float*)d_in[7];
  const float* U = (const float*)d_in[8];
  const float* S = (const float*)d_in[9];
  const float* V = (const float*)d_in[10];
  const float* bias = (const float*)d_in[11];
  float* out = (float*)d_out;

  unsigned short* Abf = (unsigned short*)d_ws;                           // 8 MB
  unsigned char* Aq = (unsigned char*)d_ws + (size_t)TOKENS * IN_F * 2;  // 4 MB
  float* t = (float*)((char*)d_ws + (size_t)TOKENS * IN_F * 3);          // 128 KB

  hipMemsetAsync(t, 0, TOKENS * RANK * sizeof(float), stream);
  k_quant<<<(TOKENS * IN_F / 4) / 256, 256, 0, stream>>>(x, smooth, act, Abf, Aq);
  k_lr1<<<64, 256, 0, stream>>>(Abf, V, S, act, t);
  k_lr2<<<256, 256, 0, stream>>>(t, U, bias, out);
  k_outlier<<<TOKENS, 256, 0, stream>>>(Abf, orow, ocol, oval, act, out);
  k_gemm<<<1024, 512, 0, stream>>>(Aq, W, wscale, act, out);
}

// Round 7
// 191.109 us; speedup vs baseline: 1.2745x; 1.2745x over previous
//
#include <hip/hip_runtime.h>
#include <hip/hip_bf16.h>

#define TOKENS 512
#define IN_F 8192
#define OUT_F 8192
#define RANK 64
#define NNZ 8192

#define KSPLIT 4
#define KRANGE (IN_F / KSPLIT)   // 2048
#define BM 512
#define BN 64
#define BK 64
#define NT (KRANGE / BK)         // 32

typedef __attribute__((ext_vector_type(8))) short short8;
typedef __attribute__((ext_vector_type(4))) float f32x4;
typedef __attribute__((ext_vector_type(4))) int int4v;

__device__ __forceinline__ unsigned short f2bf(float f) {
  unsigned int u = __builtin_bit_cast(unsigned int, f);
  u += 0x7FFFu + ((u >> 16) & 1u);
  return (unsigned short)(u >> 16);
}
__device__ __forceinline__ float bf2f(unsigned short b) {
  unsigned int u = ((unsigned int)b) << 16;
  return __builtin_bit_cast(float, u);
}

__device__ __forceinline__ void gload_lds16(const void* g, void* l) {
  __builtin_amdgcn_global_load_lds(
      (const __attribute__((address_space(1))) unsigned int*)(g),
      (__attribute__((address_space(3))) unsigned int*)(l), 16, 0, 0);
}

#define WAIT_VM(n) asm volatile("s_waitcnt vmcnt(" #n ")" ::: "memory")
#define WAIT_LGKM0 asm volatile("s_waitcnt lgkmcnt(0)" ::: "memory")

// K1: quantize x -> x_q; bf16 copy (lr1/outlier) and i8 copy (gemm)
__global__ __launch_bounds__(256) void k_quant(const float* __restrict__ x,
                                               const float* __restrict__ smooth,
                                               const float* __restrict__ act,
                                               unsigned short* __restrict__ Abf,
                                               unsigned char* __restrict__ Aq) {
  int idx = blockIdx.x * 256 + threadIdx.x;
  int base = idx * 4;
  int col = base & (IN_F - 1);
  float a = act[0];
  float4 xx = *(const float4*)(x + base);
  float4 ss = *(const float4*)(smooth + col);
  float q0 = fminf(fmaxf(rintf((xx.x / ss.x) / a), -128.f), 127.f);
  float q1 = fminf(fmaxf(rintf((xx.y / ss.y) / a), -128.f), 127.f);
  float q2 = fminf(fmaxf(rintf((xx.z / ss.z) / a), -128.f), 127.f);
  float q3 = fminf(fmaxf(rintf((xx.w / ss.w) / a), -128.f), 127.f);
  ushort4 o;
  o.x = f2bf(q0); o.y = f2bf(q1); o.z = f2bf(q2); o.w = f2bf(q3);
  *(ushort4*)(Abf + base) = o;
  int i0 = (int)q0, i1 = (int)q1, i2 = (int)q2, i3 = (int)q3;
  unsigned int p = (i0 & 0xFF) | ((i1 & 0xFF) << 8) | ((i2 & 0xFF) << 16) |
                   ((unsigned)(i3 & 0xFF) << 24);
  *(unsigned int*)(Aq + base) = p;
}

// K2: t[512][64] = (x_dq @ V) * S*a   (64 blocks, atomic K-split accum)
__global__ __launch_bounds__(256) void k_lr1(const unsigned short* __restrict__ Abf,
                                             const float* __restrict__ V,
                                             const float* __restrict__ S,
                                             const float* __restrict__ act,
                                             float* __restrict__ t) {
  int bid = blockIdx.x;
  int mb = (bid & 3) * 128;
  int kb0 = (bid >> 2) * 512;
  int tid = threadIdx.x, w = tid >> 6, l = tid & 63;
  int lr = l & 15, lg = l >> 4;
  f32x4 acc[2][4] = {};
  for (int ks = 0; ks < 16; ++ks) {
    int kb = kb0 + ks * 32;
    short8 af[2];
#pragma unroll
    for (int fi = 0; fi < 2; ++fi) {
      int row = mb + w * 32 + fi * 16 + lr;
      af[fi] = *(const short8*)(Abf + (size_t)row * IN_F + kb + lg * 8);
    }
    short8 bfr[4];
#pragma unroll
    for (int fj = 0; fj < 4; ++fj) {
      int rk = fj * 16 + lr;
      short8 bv;
#pragma unroll
      for (int j = 0; j < 8; ++j)
        bv[j] = (short)f2bf(V[(size_t)(kb + lg * 8 + j) * RANK + rk]);
      bfr[fj] = bv;
    }
#pragma unroll
    for (int fi = 0; fi < 2; ++fi)
#pragma unroll
      for (int fj = 0; fj < 4; ++fj)
        acc[fi][fj] = __builtin_amdgcn_mfma_f32_16x16x32_bf16(af[fi], bfr[fj], acc[fi][fj], 0, 0, 0);
  }
  float a = act[0];
#pragma unroll
  for (int fi = 0; fi < 2; ++fi)
#pragma unroll
    for (int fj = 0; fj < 4; ++fj) {
      int rk = fj * 16 + lr;
      float sc = a * S[rk];
#pragma unroll
      for (int r = 0; r < 4; ++r) {
        int tok = mb + w * 32 + fi * 16 + lg * 4 + r;
        atomicAdd(t + tok * RANK + rk, acc[fi][fj][r] * sc);
      }
    }
}

// K3: out = bias + t @ U^T   (first writer of out)
__global__ __launch_bounds__(256) void k_lr2(const float* __restrict__ t,
                                             const float* __restrict__ U,
                                             const float* __restrict__ bias,
                                             float* __restrict__ out) {
  int bid = blockIdx.x;
  int mb = (bid & 3) * 128;
  int nb = (bid >> 2) * 128;
  int tid = threadIdx.x, w = tid >> 6, l = tid & 63;
  int lr = l & 15, lg = l >> 4;
  int wm = w >> 1, wn = w & 1;
  f32x4 acc[4][4] = {};
#pragma unroll
  for (int kk = 0; kk < 2; ++kk) {
    short8 af[4], bfr[4];
#pragma unroll
    for (int fi = 0; fi < 4; ++fi) {
      int row = mb + wm * 64 + fi * 16 + lr;
      const float4* tp = (const float4*)(t + (size_t)row * RANK + kk * 32 + lg * 8);
      float4 t0 = tp[0], t1 = tp[1];
      af[fi][0] = f2bf(t0.x); af[fi][1] = f2bf(t0.y);
      af[fi][2] = f2bf(t0.z); af[fi][3] = f2bf(t0.w);
      af[fi][4] = f2bf(t1.x); af[fi][5] = f2bf(t1.y);
      af[fi][6] = f2bf(t1.z); af[fi][7] = f2bf(t1.w);
    }
#pragma unroll
    for (int fj = 0; fj < 4; ++fj) {
      int row = nb + wn * 64 + fj * 16 + lr;
      const float4* up = (const float4*)(U + (size_t)row * RANK + kk * 32 + lg * 8);
      float4 u0 = up[0], u1 = up[1];
      bfr[fj][0] = f2bf(u0.x); bfr[fj][1] = f2bf(u0.y);
      bfr[fj][2] = f2bf(u0.z); bfr[fj][3] = f2bf(u0.w);
      bfr[fj][4] = f2bf(u1.x); bfr[fj][5] = f2bf(u1.y);
      bfr[fj][6] = f2bf(u1.z); bfr[fj][7] = f2bf(u1.w);
    }
#pragma unroll
    for (int fi = 0; fi < 4; ++fi)
#pragma unroll
      for (int fj = 0; fj < 4; ++fj)
        acc[fi][fj] = __builtin_amdgcn_mfma_f32_16x16x32_bf16(af[fi], bfr[fj], acc[fi][fj], 0, 0, 0);
  }
#pragma unroll
  for (int fj = 0; fj < 4; ++fj) {
    int o = nb + wn * 64 + fj * 16 + lr;
    float b = bias[o];
#pragma unroll
    for (int fi = 0; fi < 4; ++fi)
#pragma unroll
      for (int r = 0; r < 4; ++r) {
        int tok = mb + wm * 64 + fi * 16 + lg * 4 + r;
        out[(size_t)tok * OUT_F + o] = b + acc[fi][fj][r];
      }
  }
}

// K4: outliers + partial merge — per-token LDS accumulator for outliers,
// then one coalesced RMW pass that also sums the 4 int32 GEMM partials.
__global__ __launch_bounds__(256) void k_outlier_merge(
    const unsigned short* __restrict__ Abf, const int* __restrict__ rows,
    const int* __restrict__ cols, const float* __restrict__ vals,
    const float* __restrict__ act, const float* __restrict__ wscale,
    const int* __restrict__ part, float* __restrict__ out) {
  __shared__ float accr[OUT_F];
  int tk = blockIdx.x;
  for (int i = threadIdx.x; i < OUT_F; i += 256) accr[i] = 0.f;
  __syncthreads();
  float a = act[0];
  for (int i = threadIdx.x; i < NNZ; i += 256) {
    int r = rows[i], c = cols[i];
    float v = vals[i];
    float xq = bf2f(Abf[(size_t)tk * IN_F + c]);
    atomicAdd(accr + r, a * xq * v);
  }
  __syncthreads();
  float* orow = out + (size_t)tk * OUT_F;
  const int* p0 = part + (size_t)tk * OUT_F;
  const int* p1 = p0 + (size_t)TOKENS * OUT_F;
  const int* p2 = p1 + (size_t)TOKENS * OUT_F;
  const int* p3 = p2 + (size_t)TOKENS * OUT_F;
  for (int i = threadIdx.x * 4; i < OUT_F; i += 1024) {
    int4v s0 = *(const int4v*)(p0 + i);
    int4v s1 = *(const int4v*)(p1 + i);
    int4v s2 = *(const int4v*)(p2 + i);
    int4v s3 = *(const int4v*)(p3 + i);
    float4 ws = *(const float4*)(wscale + i);
    float4 ov = *(const float4*)(orow + i);
    ov.x += accr[i + 0] + (float)(s0[0] + s1[0] + s2[0] + s3[0]) * a * ws.x;
    ov.y += accr[i + 1] + (float)(s0[1] + s1[1] + s2[1] + s3[1]) * a * ws.y;
    ov.z += accr[i + 2] + (float)(s0[2] + s1[2] + s2[2] + s3[2]) * a * ws.z;
    ov.w += accr[i + 3] + (float)(s0[3] + s1[3] + s2[3] + s3[3]) * a * ws.w;
    *(float4*)(orow + i) = ov;
  }
}

// K5: part[ks] = x_q @ Wq[:, ks-slice]^T (int32, exact); i8 MFMA, BM=512
// (W read exactly once), BN=64, KSPLIT=4, grid 512 = 2 blocks/CU,
// counted-vmcnt pipeline, raw s_barrier, setprio, free-2-way LDS swizzle,
// streaming (non-atomic) partial stores.
__global__ __launch_bounds__(512, 4) void k_gemm(const unsigned char* __restrict__ Aq,
                                                 const int* __restrict__ W,
                                                 int* __restrict__ part) {
  __shared__ __align__(16) unsigned char As[2][BM * BK];  // 64 KB
  __shared__ __align__(16) unsigned char Bs[2][BN * BK];  // 8 KB

  // bijective XCD-chunked decode: XCD pair {2k,2k+1} owns ks=k (A-slice 1MB)
  int d = blockIdx.x;
  int wg = (d & 7) * 64 + (d >> 3);   // 0..511
  int ks = wg >> 7;                   // 0..3
  int nb = wg & 127;                  // 0..127
  int kb0 = ks * KRANGE;

  int tid = threadIdx.x, w = tid >> 6, l = tid & 63;
  int lr = l & 15, lg = l >> 4;
  int wm = w >> 1, wn = w & 1;        // 4M x 2N waves; wave tile 128x32

  int4v acc[8][2] = {};
  int4v wa[2], wb[2];

  const int rB = tid >> 3;            // W row 0..63
  const int kcB = (tid & 7) * 8;      // elem offset within BK

  auto LOAD_W = [&](int4v (&wr)[2], int kb) {
    const int* wp = W + (size_t)(nb * BN + rB) * IN_F + kb + kcB;
    wr[0] = *(const int4v*)wp;
    wr[1] = *(const int4v*)(wp + 4);
  };
  // A i8 -> LDS direct; linear dest, pre-swizzled source (u ^= (r>>1)&3)
  auto STAGE_A = [&](int buf, int kb) {
#pragma unroll
    for (int i = 0; i < 4; ++i) {
      int ubase = i * 512 + w * 64;
      int ell = ubase + l;
      int r = ell >> 2, up = ell & 3;
      int u = up ^ ((r >> 1) & 3);
      gload_lds16(Aq + (size_t)r * IN_F + kb + u * 16, &As[buf][(size_t)ubase * 16]);
    }
  };
  auto WRITE_B = [&](int buf, const int4v (&wr)[2]) {
    unsigned int w0 = 0, w1 = 0;
#pragma unroll
    for (int j = 0; j < 4; ++j) w0 |= ((unsigned)(wr[0][j] & 0xFF)) << (8 * j);
#pragma unroll
    for (int j = 0; j < 4; ++j) w1 |= ((unsigned)(wr[1][j] & 0xFF)) << (8 * j);
    int u = kcB >> 4, sub = (kcB >> 3) & 1;
    int us = u ^ ((rB >> 1) & 3);
    uint2 val; val.x = w0; val.y = w1;
    *(uint2*)(&Bs[buf][(size_t)rB * BK + us * 16 + sub * 8]) = val;
  };
  auto LDFA = [&](int buf, int row) -> int4v {
    int u = lg ^ ((row >> 1) & 3);
    return *(const int4v*)(&As[buf][(size_t)row * BK + u * 16]);
  };
  auto LDFB = [&](int buf, int row) -> int4v {
    int u = lg ^ ((row >> 1) & 3);
    return *(const int4v*)(&Bs[buf][(size_t)row * BK + u * 16]);
  };
  auto COMPUTE = [&](int buf) {
    __builtin_amdgcn_s_setprio(1);
    int4v b0 = LDFB(buf, wn * 32 + lr);
    int4v b1 = LDFB(buf, wn * 32 + 16 + lr);
#pragma unroll
    for (int fi = 0; fi < 8; ++fi) {
      int4v af = LDFA(buf, wm * 128 + fi * 16 + lr);
      acc[fi][0] = __builtin_amdgcn_mfma_i32_16x16x64_i8(af, b0, acc[fi][0], 0, 0, 0);
      acc[fi][1] = __builtin_amdgcn_mfma_i32_16x16x64_i8(af, b1, acc[fi][1], 0, 0, 0);
    }
    __builtin_amdgcn_s_setprio(0);
  };

  // prologue — steady-state invariant at loop top: 2 W loads outstanding
  LOAD_W(wa, kb0);                 // [2W0]
  STAGE_A(0, kb0);                 // [2W0, 4A0]
  WAIT_VM(4);                      // W0 ready
  WRITE_B(0, wa);
  LOAD_W(wa, kb0 + BK);            // [4A0, 2W1]
  WAIT_VM(2);                      // A0 staged
  WAIT_LGKM0;
  __builtin_amdgcn_s_barrier();

#define ITER(kt, CUR, wcur, wnxt)                                   \
  {                                                                 \
    STAGE_A(CUR ^ 1, kb0 + (((kt) + 1) & (NT - 1)) * BK);           \
    LOAD_W(wnxt, kb0 + (((kt) + 2) & (NT - 1)) * BK);               \
    COMPUTE(CUR);                                                   \
    WAIT_VM(6);                                                     \
    WRITE_B(CUR ^ 1, wcur);                                         \
    WAIT_VM(2);                                                     \
    WAIT_LGKM0;                                                     \
    __builtin_amdgcn_s_barrier();                                   \
  }

  for (int kt = 0; kt < NT; kt += 2) {
    ITER(kt, 0, wa, wb);
    ITER(kt + 1, 1, wb, wa);
  }
#undef ITER

  int* pp = part + (size_t)ks * TOKENS * OUT_F;
#pragma unroll
  for (int fj = 0; fj < 2; ++fj) {
    int o = nb * BN + wn * 32 + fj * 16 + lr;
#pragma unroll
    for (int fi = 0; fi < 8; ++fi)
#pragma unroll
      for (int rr = 0; rr < 4; ++rr) {
        int tok = wm * 128 + fi * 16 + lg * 4 + rr;
        pp[(size_t)tok * OUT_F + o] = acc[fi][fj][rr];
      }
  }
}

extern "C" void kernel_launch(void* const* d_in, const int* in_sizes, int n_in,
                              void* d_out, int out_size, void* d_ws, size_t ws_size,
                              hipStream_t stream) {
  const float* x = (const float*)d_in[0];
  const int* W = (const int*)d_in[1];
  const float* wscale = (const float*)d_in[2];
  const float* smooth = (const float*)d_in[3];
  const float* act = (const float*)d_in[4];
  const int* orow = (const int*)d_in[5];
  const int* ocol = (const int*)d_in[6];
  const float* oval = (const float*)d_in[7];
  const float* U = (const float*)d_in[8];
  const float* S = (const float*)d_in[9];
  const float* V = (const float*)d_in[10];
  const float* bias = (const float*)d_in[11];
  float* out = (float*)d_out;

  unsigned short* Abf = (unsigned short*)d_ws;                           // 8 MB
  unsigned char* Aq = (unsigned char*)d_ws + (size_t)TOKENS * IN_F * 2;  // 4 MB
  float* t = (float*)((char*)d_ws + (size_t)TOKENS * IN_F * 3);          // 128 KB
  int* part = (int*)((char*)d_ws + (size_t)TOKENS * IN_F * 3 + (size_t)TOKENS * RANK * 4);  // 64 MB

  hipMemsetAsync(t, 0, TOKENS * RANK * sizeof(float), stream);
  k_quant<<<(TOKENS * IN_F / 4) / 256, 256, 0, stream>>>(x, smooth, act, Abf, Aq);
  k_gemm<<<512, 512, 0, stream>>>(Aq, W, part);
  k_lr1<<<64, 256, 0, stream>>>(Abf, V, S, act, t);
  k_lr2<<<256, 256, 0, stream>>>(t, U, bias, out);
  k_outlier_merge<<<TOKENS, 256, 0, stream>>>(Abf, orow, ocol, oval, act,
                                              wscale, part, out);
}